// Round 1
// baseline (193.939 us; speedup 1.0000x reference)
//
#include <hip/hip_runtime.h>
#include <math.h>

#define VOCAB 50000
#define D 300
#define L 256
#define LT 8
#define B 256
#define NHOPS 6
#define NCLS 3

#define NT 320   // 5 waves
#define NW 5

__launch_bounds__(NT, 1)
__global__ void memnet_kernel(
    const float* __restrict__ emb,
    const float* __restrict__ w_lin,
    const float* __restrict__ b_lin,
    const float* __restrict__ w_att,
    const float* __restrict__ b_att,
    const float* __restrict__ w_out,
    const float* __restrict__ b_out,
    const int* __restrict__ ctx_ids,
    const int* __restrict__ ctx_len,
    const int* __restrict__ tgt_ids,
    const int* __restrict__ tgt_len,
    const int* __restrict__ tgt_loc,
    float* __restrict__ out)
{
    __shared__ float vec[D];     // current hop vector
    __shared__ float av[L];      // alpha[l] * vloc[l]
    __shared__ float s0[L];      // hop-invariant content score term
    __shared__ float vloc[L];
    __shared__ float wattA[D];
    __shared__ float wattB[D];
    __shared__ int   ctx[L];
    __shared__ float red[NW];

    const int b    = blockIdx.x;
    const int t    = threadIdx.x;
    const int lane = t & 63;
    const int wave = t >> 6;

    const int clen = ctx_len[b];
    const int tlen = tgt_len[b];
    const int loc  = tgt_loc[b];
    const float flen = (float)clen;

    // ---- setup: stage ctx ids, w_att halves, vloc, v_aspect ----
    if (t < L) {
        ctx[t] = ctx_ids[b * L + t];
        float v = 0.f;
        if (t < clen) v = 1.f - fabsf((float)(t - loc)) / flen;
        vloc[t] = v;
    }
    if (t < D) {
        wattA[t] = w_att[t];
        wattB[t] = w_att[D + t];
        // v_aspect: masked mean of target embeddings
        float s = 0.f;
        for (int j = 0; j < tlen; ++j) {
            s += emb[(long)tgt_ids[b * LT + j] * D + t];
        }
        vec[t] = s / (float)tlen;
    }
    __syncthreads();

    // ---- hop-invariant: s0[l] = vloc[l] * dot(emb[ctx[l]], wattA) ----
    // each wave handles l = wave, wave+NW, ... ; lanes stride d (coalesced)
    for (int l = wave; l < L; l += NW) {
        float p = 0.f;
        const float* row = emb + (long)ctx[l] * D;
        for (int d = lane; d < D; d += 64) p += row[d] * wattA[d];
        #pragma unroll
        for (int off = 32; off > 0; off >>= 1) p += __shfl_down(p, off, 64);
        if (lane == 0) s0[l] = vloc[l] * p;
    }
    __syncthreads();

    const float batt = b_att[0];

    // ---- hops ----
    for (int hop = 0; hop < NHOPS; ++hop) {
        // tb = dot(vec, wattB) + batt   (block reduction)
        float p = 0.f;
        if (t < D) p = vec[t] * wattB[t];
        #pragma unroll
        for (int off = 32; off > 0; off >>= 1) p += __shfl_down(p, off, 64);
        if (lane == 0) red[wave] = p;
        __syncthreads();
        const float tb = red[0] + red[1] + red[2] + red[3] + red[4] + batt;
        __syncthreads();   // protect red before reuse

        // scores + softmax over valid l (thread t owns l = t)
        float sc = -1e30f;
        if (t < clen) sc = tanhf(s0[t] + tb);
        float m = sc;
        #pragma unroll
        for (int off = 32; off > 0; off >>= 1) m = fmaxf(m, __shfl_down(m, off, 64));
        if (lane == 0) red[wave] = m;
        __syncthreads();
        const float mx = fmaxf(fmaxf(fmaxf(red[0], red[1]), fmaxf(red[2], red[3])), red[4]);
        __syncthreads();

        float e = 0.f;
        if (t < clen) e = expf(sc - mx);
        float s = e;
        #pragma unroll
        for (int off = 32; off > 0; off >>= 1) s += __shfl_down(s, off, 64);
        if (lane == 0) red[wave] = s;
        __syncthreads();
        const float ssum = red[0] + red[1] + red[2] + red[3] + red[4];
        if (t < L) av[t] = (e / ssum) * vloc[t];
        __syncthreads();

        // new vec[d] = attn_out[d] + linear_out[d]
        float nv = 0.f;
        if (t < D) {
            // linear: vec @ w_lin + b_lin   (coalesced column reads)
            float l0 = 0.f, l1 = 0.f, l2 = 0.f, l3 = 0.f;
            for (int i = 0; i < D; i += 4) {
                l0 += vec[i    ] * w_lin[(i    ) * D + t];
                l1 += vec[i + 1] * w_lin[(i + 1) * D + t];
                l2 += vec[i + 2] * w_lin[(i + 2) * D + t];
                l3 += vec[i + 3] * w_lin[(i + 3) * D + t];
            }
            const float lin = b_lin[t] + (l0 + l1) + (l2 + l3);

            // attention readout: sum_l av[l] * emb[ctx[l]][d]
            float a0 = 0.f, a1 = 0.f, a2 = 0.f, a3 = 0.f;
            int l = 0;
            for (; l + 3 < clen; l += 4) {
                a0 += av[l    ] * emb[(long)ctx[l    ] * D + t];
                a1 += av[l + 1] * emb[(long)ctx[l + 1] * D + t];
                a2 += av[l + 2] * emb[(long)ctx[l + 2] * D + t];
                a3 += av[l + 3] * emb[(long)ctx[l + 3] * D + t];
            }
            for (; l < clen; ++l) a0 += av[l] * emb[(long)ctx[l] * D + t];
            nv = lin + (a0 + a1) + (a2 + a3);
        }
        __syncthreads();   // everyone done reading vec
        if (t < D) vec[t] = nv;
        __syncthreads();
    }

    // ---- logits = vec @ w_out + b_out ----
    if (t < NCLS) {
        float s = b_out[t];
        for (int i = 0; i < D; ++i) s += vec[i] * w_out[i * NCLS + t];
        out[b * NCLS + t] = s;
    }
}

extern "C" void kernel_launch(void* const* d_in, const int* in_sizes, int n_in,
                              void* d_out, int out_size, void* d_ws, size_t ws_size,
                              hipStream_t stream) {
    const float* emb     = (const float*)d_in[0];
    const float* w_lin   = (const float*)d_in[1];
    const float* b_lin   = (const float*)d_in[2];
    const float* w_att   = (const float*)d_in[3];
    const float* b_att   = (const float*)d_in[4];
    const float* w_out   = (const float*)d_in[5];
    const float* b_out   = (const float*)d_in[6];
    const int*   ctx_ids = (const int*)d_in[7];
    const int*   ctx_len = (const int*)d_in[8];
    const int*   tgt_ids = (const int*)d_in[9];
    const int*   tgt_len = (const int*)d_in[10];
    const int*   tgt_loc = (const int*)d_in[11];

    memnet_kernel<<<B, NT, 0, stream>>>(emb, w_lin, b_lin, w_att, b_att,
                                        w_out, b_out, ctx_ids, ctx_len,
                                        tgt_ids, tgt_len, tgt_loc,
                                        (float*)d_out);
}

// Round 2
// 72.353 us; speedup vs baseline: 2.6804x; 2.6804x over previous
//
#include <hip/hip_runtime.h>
#include <math.h>

#define VOCAB 50000
#define D 300
#define D4 75          // D/4
#define L 256
#define LT 8
#define B 256
#define NHOPS 6
#define NCLS 3

#define NT 1024        // 16 waves
#define NWAVES 16
#define NC 13          // reduction chunks (t = c*75 + dq decomposition)

__device__ __forceinline__ float wave_sum(float p) {
    #pragma unroll
    for (int off = 32; off > 0; off >>= 1) p += __shfl_down(p, off, 64);
    return p;
}

__launch_bounds__(NT, 1)
__global__ void memnet_kernel(
    const float* __restrict__ emb,
    const float* __restrict__ w_lin,
    const float* __restrict__ b_lin,
    const float* __restrict__ w_att,
    const float* __restrict__ b_att,
    const float* __restrict__ w_out,
    const float* __restrict__ b_out,
    const int* __restrict__ ctx_ids,
    const int* __restrict__ ctx_len,
    const int* __restrict__ tgt_ids,
    const int* __restrict__ tgt_len,
    const int* __restrict__ tgt_loc,
    float* __restrict__ out)
{
    __shared__ float  vec[D];
    __shared__ float  av[L];
    __shared__ float  s0[L];
    __shared__ float  vloc[L];
    __shared__ float4 wa4[D4];
    __shared__ float  wattB[D];
    __shared__ int    ctx[L];
    __shared__ float4 partL[NC][D4];
    __shared__ float4 partA[NC][D4];
    __shared__ float  redA[NWAVES];
    __shared__ float  redB[NWAVES];

    const int b    = blockIdx.x;
    const int t    = threadIdx.x;
    const int lane = t & 63;
    const int w    = t >> 6;
    const int dq   = t % D4;       // quad index: owns d = 4*dq .. 4*dq+3
    const int c    = t / D4;       // chunk index 0..13 (c==13 -> 49 spare threads)

    const int clen = ctx_len[b];
    const int tlen = tgt_len[b];
    const int loc  = tgt_loc[b];
    const float flen = (float)clen;

    // ---- setup ----
    if (t < L) {
        ctx[t] = ctx_ids[b * L + t];
        float v = 0.f;
        if (t < clen) v = 1.f - fabsf((float)(t - loc)) / flen;
        vloc[t] = v;
    }
    if (t < D4) wa4[t] = ((const float4*)w_att)[t];
    if (t < D)  wattB[t] = w_att[D + t];

    // v_aspect partials: chunk c == target index j
    if (c < LT) {
        float4 p = {0.f, 0.f, 0.f, 0.f};
        if (c < tlen) {
            const float4* row = (const float4*)(emb + (long)tgt_ids[b * LT + c] * D);
            p = row[dq];
        }
        partL[c][dq] = p;
    }
    __syncthreads();

    // v_aspect reduce -> vec
    if (t < D4) {
        float4 s = {0.f, 0.f, 0.f, 0.f};
        for (int j = 0; j < LT; ++j) {
            float4 q = partL[j][t];
            s.x += q.x; s.y += q.y; s.z += q.z; s.w += q.w;
        }
        const float inv = 1.f / (float)tlen;
        vec[4 * t + 0] = s.x * inv;
        vec[4 * t + 1] = s.y * inv;
        vec[4 * t + 2] = s.z * inv;
        vec[4 * t + 3] = s.w * inv;
    }

    // s0[l] = vloc[l] * dot(emb[ctx[l]], w_att[:D]) ; wave w does l = w, w+16, ...
    for (int l0 = w; l0 < L; l0 += 2 * NWAVES) {
        const int l1 = l0 + NWAVES;
        const float4* r0 = (const float4*)(emb + (long)ctx[l0] * D);
        const float4* r1 = (const float4*)(emb + (long)ctx[l1] * D);
        const float4 a0 = r0[lane];
        const float4 a1 = r1[lane];
        const float4 wv = wa4[lane];
        float p0 = a0.x * wv.x + a0.y * wv.y + a0.z * wv.z + a0.w * wv.w;
        float p1 = a1.x * wv.x + a1.y * wv.y + a1.z * wv.z + a1.w * wv.w;
        if (lane < D4 - 64) {   // 11 tail quads
            const float4 b0 = r0[64 + lane];
            const float4 b1 = r1[64 + lane];
            const float4 w2 = wa4[64 + lane];
            p0 += b0.x * w2.x + b0.y * w2.y + b0.z * w2.z + b0.w * w2.w;
            p1 += b1.x * w2.x + b1.y * w2.y + b1.z * w2.z + b1.w * w2.w;
        }
        p0 = wave_sum(p0);
        p1 = wave_sum(p1);
        if (lane == 0) {
            s0[l0] = vloc[l0] * p0;
            s0[l1] = vloc[l1] * p1;
        }
    }
    const float batt = b_att[0];
    __syncthreads();

    // ---- hops ----
    for (int hop = 0; hop < NHOPS; ++hop) {
        // (1) tb partial: dot(vec, wattB)
        float p = (t < D) ? vec[t] * wattB[t] : 0.f;
        p = wave_sum(p);
        if (lane == 0) redA[w] = p;
        __syncthreads();

        // (2) linear partials (long loads issued first), then scores
        const float tb = redA[0] + redA[1] + redA[2] + redA[3] + redA[4] + batt;

        float4 LP = {0.f, 0.f, 0.f, 0.f};
        if (c < NC) {
            int i = c;
            for (; i + NC < D; i += 2 * NC) {
                const float s_a = vec[i];
                const float s_b = vec[i + NC];
                const float4 wr_a = ((const float4*)(w_lin + (long)i * D))[dq];
                const float4 wr_b = ((const float4*)(w_lin + (long)(i + NC) * D))[dq];
                LP.x += s_a * wr_a.x; LP.y += s_a * wr_a.y;
                LP.z += s_a * wr_a.z; LP.w += s_a * wr_a.w;
                LP.x += s_b * wr_b.x; LP.y += s_b * wr_b.y;
                LP.z += s_b * wr_b.z; LP.w += s_b * wr_b.w;
            }
            if (i < D) {
                const float s_a = vec[i];
                const float4 wr_a = ((const float4*)(w_lin + (long)i * D))[dq];
                LP.x += s_a * wr_a.x; LP.y += s_a * wr_a.y;
                LP.z += s_a * wr_a.z; LP.w += s_a * wr_a.w;
            }
        }

        // scores: tanh in (-1,1) -> exp always safe, no max pass needed
        float e = 0.f;
        if (t < clen) e = __expf(tanhf(s0[t] + tb));
        float sp = wave_sum(e);
        if (lane == 0) redB[w] = sp;
        __syncthreads();

        // (3) av + store linear partials
        const float ssum = redB[0] + redB[1] + redB[2] + redB[3];
        const float rinv = 1.f / ssum;
        if (t < L) av[t] = e * vloc[t] * rinv;
        if (c < NC) partL[c][dq] = LP;
        __syncthreads();

        // (4) attention gather partials: l = c, c+13, ...
        if (c < NC) {
            float4 AP = {0.f, 0.f, 0.f, 0.f};
            int l = c;
            for (; l + NC < clen; l += 2 * NC) {
                const float a0 = av[l];
                const float a1 = av[l + NC];
                const float4 e0 = ((const float4*)(emb + (long)ctx[l] * D))[dq];
                const float4 e1 = ((const float4*)(emb + (long)ctx[l + NC] * D))[dq];
                AP.x += a0 * e0.x; AP.y += a0 * e0.y;
                AP.z += a0 * e0.z; AP.w += a0 * e0.w;
                AP.x += a1 * e1.x; AP.y += a1 * e1.y;
                AP.z += a1 * e1.z; AP.w += a1 * e1.w;
            }
            if (l < clen) {
                const float a0 = av[l];
                const float4 e0 = ((const float4*)(emb + (long)ctx[l] * D))[dq];
                AP.x += a0 * e0.x; AP.y += a0 * e0.y;
                AP.z += a0 * e0.z; AP.w += a0 * e0.w;
            }
            partA[c][dq] = AP;
        }
        __syncthreads();

        // (5) combine -> new vec
        if (t < D4) {
            float4 acc = ((const float4*)b_lin)[t];
            #pragma unroll
            for (int cc = 0; cc < NC; ++cc) {
                const float4 x = partL[cc][t];
                const float4 y = partA[cc][t];
                acc.x += x.x + y.x; acc.y += x.y + y.y;
                acc.z += x.z + y.z; acc.w += x.w + y.w;
            }
            vec[4 * t + 0] = acc.x;
            vec[4 * t + 1] = acc.y;
            vec[4 * t + 2] = acc.z;
            vec[4 * t + 3] = acc.w;
        }
        __syncthreads();
    }

    // ---- logits ----
    if (w < NCLS) {
        float p = 0.f;
        for (int d = lane; d < D; d += 64) p += vec[d] * w_out[d * NCLS + w];
        p = wave_sum(p);
        if (lane == 0) out[b * NCLS + w] = p + b_out[w];
    }
}

extern "C" void kernel_launch(void* const* d_in, const int* in_sizes, int n_in,
                              void* d_out, int out_size, void* d_ws, size_t ws_size,
                              hipStream_t stream) {
    const float* emb     = (const float*)d_in[0];
    const float* w_lin   = (const float*)d_in[1];
    const float* b_lin   = (const float*)d_in[2];
    const float* w_att   = (const float*)d_in[3];
    const float* b_att   = (const float*)d_in[4];
    const float* w_out   = (const float*)d_in[5];
    const float* b_out   = (const float*)d_in[6];
    const int*   ctx_ids = (const int*)d_in[7];
    const int*   ctx_len = (const int*)d_in[8];
    const int*   tgt_ids = (const int*)d_in[9];
    const int*   tgt_len = (const int*)d_in[10];
    const int*   tgt_loc = (const int*)d_in[11];

    memnet_kernel<<<B, NT, 0, stream>>>(emb, w_lin, b_lin, w_att, b_att,
                                        w_out, b_out, ctx_ids, ctx_len,
                                        tgt_ids, tgt_len, tgt_loc,
                                        (float*)d_out);
}

// Round 3
// 71.443 us; speedup vs baseline: 2.7146x; 1.0127x over previous
//
#include <hip/hip_runtime.h>
#include <math.h>

typedef unsigned short u16;
typedef unsigned int   u32;

#define D      300
#define LQ     75      // float4 quads per row
#define L      256
#define LT     8
#define B      256
#define NHOPS  6
#define NCLS   3
#define NT     1024

// dynamic LDS layout (bytes)
#define OFF_VEC    0        // f32[300]   1200 (+pad)
#define OFF_WATTB  1216     // f32[300]   1200 (+pad)
#define OFF_AV     2432     // f32[256]   1024   (vloc during staging)
#define OFF_S0     3456     // f32[256]   1024
#define OFF_REDA   4480     // f32[16]
#define OFF_REDB   4544     // f32[16]
#define OFF_PART   4608     // f32[3*300] 3600   (alias: ctx[256] + wattA[300] during staging)
#define OFF_CTX    4608
#define OFF_WATTA  5632     // 16B aligned
#define OFF_E      8208     // bf16[256*300] 153600
#define SMEM_BYTES (OFF_E + L * D * 2)   // 161808 <= 163840

__device__ __forceinline__ float wave_sum(float p) {
    #pragma unroll
    for (int off = 32; off > 0; off >>= 1) p += __shfl_down(p, off, 64);
    return p;
}
__device__ __forceinline__ float bf2f(u16 u) {
    return __uint_as_float(((u32)u) << 16);
}
__device__ __forceinline__ u16 f2bf(float f) {   // round-to-nearest-even
    u32 b = __float_as_uint(f);
    b += 0x7FFFu + ((b >> 16) & 1u);
    return (u16)(b >> 16);
}

__launch_bounds__(NT, 1)
__global__ void cvt_wlin(const float* __restrict__ x, u16* __restrict__ o, int n) {
    int i = blockIdx.x * NT + threadIdx.x;
    if (i < n) o[i] = f2bf(x[i]);
}

template<int WBF>
__launch_bounds__(NT, 1)
__global__ void memnet_main(
    const float* __restrict__ emb,
    const float* __restrict__ w_lin,
    const u16*  __restrict__ wbf,
    const float* __restrict__ b_lin,
    const float* __restrict__ w_att,
    const float* __restrict__ b_att,
    const float* __restrict__ w_out,
    const float* __restrict__ b_out,
    const int* __restrict__ ctx_ids,
    const int* __restrict__ ctx_len,
    const int* __restrict__ tgt_ids,
    const int* __restrict__ tgt_len,
    const int* __restrict__ tgt_loc,
    float* __restrict__ out)
{
    extern __shared__ char sm[];
    float* vec_ = (float*)(sm + OFF_VEC);
    float* wB_  = (float*)(sm + OFF_WATTB);
    float* av_  = (float*)(sm + OFF_AV);
    float* s0_  = (float*)(sm + OFF_S0);
    float* redA = (float*)(sm + OFF_REDA);
    float* redB = (float*)(sm + OFF_REDB);
    float* part = (float*)(sm + OFF_PART);
    int*   ctx_ = (int*)(sm + OFF_CTX);
    float* wA_  = (float*)(sm + OFF_WATTA);
    const u16* ebase = (const u16*)(sm + OFF_E);

    const int b = blockIdx.x, t = threadIdx.x;
    const int lane = t & 63, w = t >> 6;
    const int clen = ctx_len[b], tlen = tgt_len[b], loc = tgt_loc[b];

    // ---- stage scalars/vectors: ctx ids, vloc (in av_), w_att halves ----
    if (t < L) {
        ctx_[t] = ctx_ids[b * L + t];
        float v = 0.f;
        if (t < clen) v = 1.f - fabsf((float)(t - loc)) / (float)clen;
        av_[t] = v;                                  // vloc scratch
    } else if (t < L + D) {
        wA_[t - L] = w_att[t - L];                   // w_att[0..299]
    } else if (t < L + 2 * D) {
        wB_[t - L - D] = w_att[t - L];               // w_att[300..599]
    }
    __syncthreads();

    // ---- stage ext_mem rows (bf16, vloc-premultiplied) + s0 (f32 exact) ----
    {
        const float4* emb4 = (const float4*)emb;
        const float4* wA4  = (const float4*)wA_;
        const float4 wa1 = wA4[lane];
        float4 wa2 = make_float4(0.f, 0.f, 0.f, 0.f);
        if (lane < LQ - 64) wa2 = wA4[64 + lane];
        for (int r = 0; r < 16; ++r) {
            const int l   = w * 16 + r;
            const int cid = ctx_[l];
            const float vl = av_[l];
            const float4 v1 = emb4[(long)cid * LQ + lane];
            float4 v2 = make_float4(0.f, 0.f, 0.f, 0.f);
            if (lane < LQ - 64) v2 = emb4[(long)cid * LQ + 64 + lane];
            float p = v1.x * wa1.x + v1.y * wa1.y + v1.z * wa1.z + v1.w * wa1.w
                    + v2.x * wa2.x + v2.y * wa2.y + v2.z * wa2.z + v2.w * wa2.w;
            p = wave_sum(p);
            if (lane == 0) s0_[l] = vl * p;
            u16* erow = (u16*)(sm + OFF_E + l * (D * 2));
            ushort4 q;
            q.x = f2bf(v1.x * vl); q.y = f2bf(v1.y * vl);
            q.z = f2bf(v1.z * vl); q.w = f2bf(v1.w * vl);
            *(ushort4*)(erow + 4 * lane) = q;
            if (lane < LQ - 64) {
                ushort4 q2;
                q2.x = f2bf(v2.x * vl); q2.y = f2bf(v2.y * vl);
                q2.z = f2bf(v2.z * vl); q2.w = f2bf(v2.w * vl);
                *(ushort4*)(erow + 4 * (64 + lane)) = q2;
            }
        }
    }

    // ---- v_aspect -> vec, plus first-hop tb partials ----
    if (t < 320) {
        float vv = 0.f, p = 0.f;
        if (t < D) {
            float s = 0.f;
            for (int j = 0; j < tlen; ++j)
                s += emb[(long)tgt_ids[b * LT + j] * D + t];
            vv = s / (float)tlen;
            vec_[t] = vv;
            p = vv * wB_[t];
        }
        p = wave_sum(p);
        if (lane == 0) redA[w] = p;
    }
    const float batt = b_att[0];

    const int c = t / D;          // chunk 0..3 (c==3 idle in heavy phases)
    const int d = t - c * D;      // column 0..299

    // ---- hops ----
    for (int hop = 0; hop < NHOPS; ++hop) {
        __syncthreads();   // vec, redA, (E, s0 at hop 0) ready
        const float tb = redA[0] + redA[1] + redA[2] + redA[3] + redA[4] + batt;

        // softmax (scores = tanh in (-1,1) -> exp always safe, no max pass)
        float e = 0.f;
        if (t < L) {
            if (t < clen) e = __expf(tanhf(s0_[t] + tb));
            float sp = wave_sum(e);
            if (lane == 0) redB[w] = sp;
        }
        __syncthreads();
        if (t < L) av_[t] = e / (redB[0] + redB[1] + redB[2] + redB[3]);
        __syncthreads();

        // linear (global bf16/f32 w_lin) + attention (LDS bf16 ext_mem)
        if (c < 3) {
            const int rbase = c * 100;
            float l0 = 0.f, l1 = 0.f, l2 = 0.f, l3 = 0.f;
            #pragma unroll 4
            for (int k = 0; k < 100; k += 4) {
                float w0, w1, w2, w3;
                if (WBF) {
                    w0 = bf2f(wbf[(rbase + k    ) * D + d]);
                    w1 = bf2f(wbf[(rbase + k + 1) * D + d]);
                    w2 = bf2f(wbf[(rbase + k + 2) * D + d]);
                    w3 = bf2f(wbf[(rbase + k + 3) * D + d]);
                } else {
                    w0 = w_lin[(rbase + k    ) * D + d];
                    w1 = w_lin[(rbase + k + 1) * D + d];
                    w2 = w_lin[(rbase + k + 2) * D + d];
                    w3 = w_lin[(rbase + k + 3) * D + d];
                }
                l0 += vec_[rbase + k    ] * w0;
                l1 += vec_[rbase + k + 1] * w1;
                l2 += vec_[rbase + k + 2] * w2;
                l3 += vec_[rbase + k + 3] * w3;
            }
            float a0 = 0.f, a1 = 0.f, a2 = 0.f, a3 = 0.f;
            int l = c;
            for (; l + 9 < clen; l += 12) {
                a0 += av_[l    ] * bf2f(ebase[(l    ) * D + d]);
                a1 += av_[l + 3] * bf2f(ebase[(l + 3) * D + d]);
                a2 += av_[l + 6] * bf2f(ebase[(l + 6) * D + d]);
                a3 += av_[l + 9] * bf2f(ebase[(l + 9) * D + d]);
            }
            for (; l < clen; l += 3)
                a0 += av_[l] * bf2f(ebase[l * D + d]);
            part[c * D + d] = (l0 + l1) + (l2 + l3) + (a0 + a1) + (a2 + a3);
        }
        __syncthreads();

        // combine -> new vec, and next hop's tb partials
        if (t < 320) {
            float nv = 0.f, p = 0.f;
            if (t < D) {
                nv = b_lin[t] + part[t] + part[D + t] + part[2 * D + t];
                p = nv * wB_[t];
                vec_[t] = nv;
            }
            p = wave_sum(p);
            if (lane == 0) redA[w] = p;
        }
    }
    __syncthreads();

    // ---- logits ----
    if (t < NCLS * 64) {
        const int cls = w;
        float p = 0.f;
        for (int i = lane; i < D; i += 64)
            p += vec_[i] * w_out[i * NCLS + cls];
        p = wave_sum(p);
        if (lane == 0) out[b * NCLS + cls] = p + b_out[cls];
    }
}

extern "C" void kernel_launch(void* const* d_in, const int* in_sizes, int n_in,
                              void* d_out, int out_size, void* d_ws, size_t ws_size,
                              hipStream_t stream) {
    const float* emb     = (const float*)d_in[0];
    const float* w_lin   = (const float*)d_in[1];
    const float* b_lin   = (const float*)d_in[2];
    const float* w_att   = (const float*)d_in[3];
    const float* b_att   = (const float*)d_in[4];
    const float* w_out   = (const float*)d_in[5];
    const float* b_out   = (const float*)d_in[6];
    const int*   ctx_ids = (const int*)d_in[7];
    const int*   ctx_len = (const int*)d_in[8];
    const int*   tgt_ids = (const int*)d_in[9];
    const int*   tgt_len = (const int*)d_in[10];
    const int*   tgt_loc = (const int*)d_in[11];
    float* out = (float*)d_out;

    const size_t WBYTES = (size_t)D * D * sizeof(u16);
    if (ws_size >= WBYTES) {
        u16* wbf = (u16*)d_ws;
        cvt_wlin<<<(D * D + NT - 1) / NT, NT, 0, stream>>>(w_lin, wbf, D * D);
        (void)hipFuncSetAttribute((const void*)memnet_main<1>,
                                  hipFuncAttributeMaxDynamicSharedMemorySize,
                                  SMEM_BYTES);
        memnet_main<1><<<B, NT, SMEM_BYTES, stream>>>(
            emb, w_lin, wbf, b_lin, w_att, b_att, w_out, b_out,
            ctx_ids, ctx_len, tgt_ids, tgt_len, tgt_loc, out);
    } else {
        (void)hipFuncSetAttribute((const void*)memnet_main<0>,
                                  hipFuncAttributeMaxDynamicSharedMemorySize,
                                  SMEM_BYTES);
        memnet_main<0><<<B, NT, SMEM_BYTES, stream>>>(
            emb, w_lin, (const u16*)nullptr, b_lin, w_att, b_att, w_out, b_out,
            ctx_ids, ctx_len, tgt_ids, tgt_len, tgt_loc, out);
    }
}

// Round 4
// 57.237 us; speedup vs baseline: 3.3884x; 1.2482x over previous
//
#include <hip/hip_runtime.h>
#include <math.h>

typedef unsigned short u16;
typedef unsigned int   u32;

#define D      300
#define L      256
#define LT     8
#define B      256
#define NHOPS  6
#define NCLS   3
#define NT     1024
#define ROWB   600            // E row bytes (300 bf16)
#define NCH    13             // reduction chunks
#define KCH    24             // k rows per chunk (13*24 = 312 >= 300)
#define LCH    20             // l rows per chunk (13*20 = 260 >= 256)
#define NHV    975            // 75 quads * 13 chunks heavy threads

// LDS layout (bytes)
#define OFF_E    0            // bf16 [256][300] = 153600
#define OFF_VEC  153600       // f32[312] (300 + zero pad)   1248
#define OFF_AV   154848       // f32[256]                    1024
#define OFF_P    155872       // ushort4[75*13] = 7800  (hops)
#define OFF_CTX  155872       //   alias: int[256]      (staging only)
#define OFF_WA   156896       //   alias: f32[300]      (staging only)
#define OFF_S0   158096       //   alias: f32[256]      (staging -> read once)
#define SMEM_BYTES 163672     // OFF_P + 7800

__device__ __forceinline__ float wave_sum_down(float p) {
    #pragma unroll
    for (int off = 32; off > 0; off >>= 1) p += __shfl_down(p, off, 64);
    return p;
}
__device__ __forceinline__ float wave_sum_xor(float p) {
    #pragma unroll
    for (int off = 1; off < 64; off <<= 1) p += __shfl_xor(p, off, 64);
    return p;
}
__device__ __forceinline__ u16 f2bf(float f) {   // RNE
    u32 x = __float_as_uint(f);
    x += 0x7FFFu + ((x >> 16) & 1u);
    return (u16)(x >> 16);
}

__launch_bounds__(NT, 1)
__global__ void cvt_wlin(const float* __restrict__ x, u16* __restrict__ o, int n) {
    int i = blockIdx.x * NT + threadIdx.x;
    if (i < n) o[i] = f2bf(x[i]);
}

template<int WREG>
__launch_bounds__(NT, 1)
__global__ void memnet_main(
    const float* __restrict__ emb,
    const float* __restrict__ w_lin,
    const u16*  __restrict__ wbf,
    const float* __restrict__ b_lin,
    const float* __restrict__ w_att,
    const float* __restrict__ b_att,
    const float* __restrict__ w_out,
    const float* __restrict__ b_out,
    const int* __restrict__ ctx_ids,
    const int* __restrict__ ctx_len,
    const int* __restrict__ tgt_ids,
    const int* __restrict__ tgt_len,
    const int* __restrict__ tgt_loc,
    float* __restrict__ out)
{
    extern __shared__ char sm[];
    float* vec_ = (float*)(sm + OFF_VEC);
    float* av_  = (float*)(sm + OFF_AV);
    int*   ctx_ = (int*)(sm + OFF_CTX);
    float* wA_  = (float*)(sm + OFF_WA);
    float* s0_  = (float*)(sm + OFF_S0);

    const int b = blockIdx.x, t = threadIdx.x;
    const int lane = t & 63, w = t >> 6;
    const int c  = t / 75;         // chunk 0..13
    const int dq = t - c * 75;     // column quad 0..74 (cols 4dq..4dq+3)
    const bool heavy = (t < NHV);

    const int clen = ctx_len[b], tlen = tgt_len[b], loc = tgt_loc[b];

    // ---------------- setup ----------------
    if (t < L) {
        ctx_[t] = ctx_ids[b * L + t];
        s0_[t] = 0.f;
    } else if (t < L + D) {
        wA_[t - L] = w_att[t - L];
    }
    if (t < 12) vec_[D + t] = 0.f;         // zero pad vec[300..311]
    __syncthreads();

    // ---------------- staging: E rows (bf16, vloc-premult) + s0 ----------------
    {
        const float4* wA4 = (const float4*)wA_;
        const float4 wa1 = wA4[lane];
        float4 wa2 = make_float4(0.f, 0.f, 0.f, 0.f);
        if (lane < 11) wa2 = wA4[64 + lane];
        const float rclen = 1.f / (float)clen;
        for (int l = w; l < clen; l += 16) {
            const float4* er = (const float4*)(emb + (long)ctx_[l] * D);
            const float4 v1 = er[lane];
            float4 v2 = make_float4(0.f, 0.f, 0.f, 0.f);
            if (lane < 11) v2 = er[64 + lane];
            float p = v1.x*wa1.x + v1.y*wa1.y + v1.z*wa1.z + v1.w*wa1.w
                    + v2.x*wa2.x + v2.y*wa2.y + v2.z*wa2.z + v2.w*wa2.w;
            p = wave_sum_down(p);
            const float vl = 1.f - fabsf((float)(l - loc)) * rclen;
            if (lane == 0) s0_[l] = vl * p;
            u16* erow = (u16*)(sm + OFF_E + l * ROWB);
            ushort4 q;
            q.x = f2bf(v1.x * vl); q.y = f2bf(v1.y * vl);
            q.z = f2bf(v1.z * vl); q.w = f2bf(v1.w * vl);
            *(ushort4*)(erow + 4 * lane) = q;
            if (lane < 11) {
                ushort4 q2;
                q2.x = f2bf(v2.x * vl); q2.y = f2bf(v2.y * vl);
                q2.z = f2bf(v2.z * vl); q2.w = f2bf(v2.w * vl);
                *(ushort4*)(erow + 4 * (64 + lane)) = q2;
            }
        }
    }

    // ---------------- v_aspect -> vec ----------------
    if (t < D) {
        float s = 0.f;
        for (int j = 0; j < tlen; ++j)
            s += emb[(long)tgt_ids[b * LT + j] * D + t];
        vec_[t] = s / (float)tlen;
    }

    // ---------------- W register cache (once, reused 6 hops) ----------------
    uint2 wreg[KCH];
    if (WREG && heavy) {
        const int k0 = KCH * c;
        #pragma unroll
        for (int kk = 0; kk < KCH; ++kk) {
            int k = k0 + kk; if (k > D - 1) k = D - 1;   // clamp; vec pad=0 kills dup
            wreg[kk] = *(const uint2*)((const char*)wbf + (long)k * ROWB + dq * 8);
        }
    }
    __syncthreads();

    // ---------------- per-thread persistent caches ----------------
    const float blin_r = (t < D) ? b_lin[t] : 0.f;
    float4 s0r = make_float4(0.f, 0.f, 0.f, 0.f);
    float wb0 = 0.f, wb1 = 0.f, wb2 = 0.f, wb3 = 0.f, wb4 = 0.f, batt_r = 0.f;
    if (w == 15) {
        s0r = *(const float4*)(s0_ + 4 * lane);
        wb0 = w_att[D + lane];
        wb1 = w_att[D + 64 + lane];
        wb2 = w_att[D + 128 + lane];
        wb3 = w_att[D + 192 + lane];
        if (lane < 44) wb4 = w_att[D + 256 + lane];
        batt_r = b_att[0];
    }

    // ---------------- hops ----------------
    for (int hop = 0; hop < NHOPS; ++hop) {
        // PHASE A: linear (heavy, regs) || softmax (wave 15)
        float l0_ = 0.f, l1_ = 0.f, l2_ = 0.f, l3_ = 0.f;
        if (heavy) {
            const float* vb = vec_ + KCH * c;
            #pragma unroll
            for (int g = 0; g < 6; ++g) {
                const float4 v4 = *(const float4*)(vb + 4 * g);
                #pragma unroll
                for (int j = 0; j < 4; ++j) {
                    const float vk = (j == 0) ? v4.x : (j == 1) ? v4.y
                                   : (j == 2) ? v4.z : v4.w;
                    uint2 wv;
                    if (WREG) {
                        wv = wreg[g * 4 + j];
                        l0_ += vk * __uint_as_float(wv.x << 16);
                        l1_ += vk * __uint_as_float(wv.x & 0xFFFF0000u);
                        l2_ += vk * __uint_as_float(wv.y << 16);
                        l3_ += vk * __uint_as_float(wv.y & 0xFFFF0000u);
                    } else {
                        int k = KCH * c + g * 4 + j; if (k > D - 1) k = D - 1;
                        const float4 w4 = *(const float4*)(w_lin + (long)k * D + 4 * dq);
                        l0_ += vk * w4.x; l1_ += vk * w4.y;
                        l2_ += vk * w4.z; l3_ += vk * w4.w;
                    }
                }
            }
        }
        if (w == 15) {
            float pp = vec_[lane] * wb0 + vec_[64 + lane] * wb1
                     + vec_[128 + lane] * wb2 + vec_[192 + lane] * wb3;
            if (lane < 44) pp += vec_[256 + lane] * wb4;
            const float tb = wave_sum_xor(pp) + batt_r;
            float e0 = 0.f, e1 = 0.f, e2 = 0.f, e3 = 0.f;
            {
                const int lb = 4 * lane;
                float x, E2, th;
                x = s0r.x + tb; E2 = __expf(2.f * x); th = (E2 - 1.f) / (E2 + 1.f);
                if (lb + 0 < clen) e0 = __expf(th);
                x = s0r.y + tb; E2 = __expf(2.f * x); th = (E2 - 1.f) / (E2 + 1.f);
                if (lb + 1 < clen) e1 = __expf(th);
                x = s0r.z + tb; E2 = __expf(2.f * x); th = (E2 - 1.f) / (E2 + 1.f);
                if (lb + 2 < clen) e2 = __expf(th);
                x = s0r.w + tb; E2 = __expf(2.f * x); th = (E2 - 1.f) / (E2 + 1.f);
                if (lb + 3 < clen) e3 = __expf(th);
            }
            const float tot = wave_sum_xor(e0 + e1 + e2 + e3);
            const float rinv = 1.f / tot;
            float4 a4;
            a4.x = e0 * rinv; a4.y = e1 * rinv; a4.z = e2 * rinv; a4.w = e3 * rinv;
            *(float4*)(av_ + 4 * lane) = a4;
        }
        __syncthreads();   // av ready

        // PHASE B: attention gather from LDS E + partial write
        if (heavy) {
            float a0_ = 0.f, a1_ = 0.f, a2_ = 0.f, a3_ = 0.f;
            const int lbase = LCH * c;
            const int lmax  = (clen < lbase + LCH) ? clen : (lbase + LCH);
            const char* ep  = sm + OFF_E + lbase * ROWB + dq * 8;
            const float* avp = av_ + lbase;
            float4 a4 = make_float4(0.f, 0.f, 0.f, 0.f);
            #pragma unroll
            for (int r = 0; r < LCH; ++r) {
                if (lbase + r < lmax) {
                    if ((r & 3) == 0) a4 = *(const float4*)(avp + r);
                    const float al = ((r & 3) == 0) ? a4.x : ((r & 3) == 1) ? a4.y
                                   : ((r & 3) == 2) ? a4.z : a4.w;
                    const uint2 ew = *(const uint2*)(ep + r * ROWB);
                    a0_ += al * __uint_as_float(ew.x << 16);
                    a1_ += al * __uint_as_float(ew.x & 0xFFFF0000u);
                    a2_ += al * __uint_as_float(ew.y << 16);
                    a3_ += al * __uint_as_float(ew.y & 0xFFFF0000u);
                }
            }
            const u32 lo = (u32)f2bf(l0_ + a0_) | ((u32)f2bf(l1_ + a1_) << 16);
            const u32 hi = (u32)f2bf(l2_ + a2_) | ((u32)f2bf(l3_ + a3_) << 16);
            *(uint2*)(sm + OFF_P + (dq * NCH + c) * 8) = make_uint2(lo, hi);
        }
        __syncthreads();   // partials ready

        // PHASE C: combine -> new vec
        if (t < D) {
            const int dq2 = t >> 2, j = t & 3;
            const u16* pp = (const u16*)(sm + OFF_P) + dq2 * NCH * 4 + j;
            float s = blin_r;
            #pragma unroll
            for (int cc = 0; cc < NCH; ++cc)
                s += __uint_as_float(((u32)pp[cc * 4]) << 16);
            vec_[t] = s;
        }
        __syncthreads();   // vec ready
    }

    // ---------------- logits ----------------
    if (t < NCLS * 64) {
        const int cls = w;
        float p = 0.f;
        for (int i = lane; i < D; i += 64)
            p += vec_[i] * w_out[i * NCLS + cls];
        p = wave_sum_down(p);
        if (lane == 0) out[b * NCLS + cls] = p + b_out[cls];
    }
}

extern "C" void kernel_launch(void* const* d_in, const int* in_sizes, int n_in,
                              void* d_out, int out_size, void* d_ws, size_t ws_size,
                              hipStream_t stream) {
    const float* emb     = (const float*)d_in[0];
    const float* w_lin   = (const float*)d_in[1];
    const float* b_lin   = (const float*)d_in[2];
    const float* w_att   = (const float*)d_in[3];
    const float* b_att   = (const float*)d_in[4];
    const float* w_out   = (const float*)d_in[5];
    const float* b_out   = (const float*)d_in[6];
    const int*   ctx_ids = (const int*)d_in[7];
    const int*   ctx_len = (const int*)d_in[8];
    const int*   tgt_ids = (const int*)d_in[9];
    const int*   tgt_len = (const int*)d_in[10];
    const int*   tgt_loc = (const int*)d_in[11];
    float* out = (float*)d_out;

    const size_t WBYTES = (size_t)D * D * sizeof(u16);
    if (ws_size >= WBYTES) {
        u16* wbf = (u16*)d_ws;
        cvt_wlin<<<(D * D + NT - 1) / NT, NT, 0, stream>>>(w_lin, wbf, D * D);
        (void)hipFuncSetAttribute((const void*)memnet_main<1>,
                                  hipFuncAttributeMaxDynamicSharedMemorySize,
                                  SMEM_BYTES);
        memnet_main<1><<<B, NT, SMEM_BYTES, stream>>>(
            emb, w_lin, wbf, b_lin, w_att, b_att, w_out, b_out,
            ctx_ids, ctx_len, tgt_ids, tgt_len, tgt_loc, out);
    } else {
        (void)hipFuncSetAttribute((const void*)memnet_main<0>,
                                  hipFuncAttributeMaxDynamicSharedMemorySize,
                                  SMEM_BYTES);
        memnet_main<0><<<B, NT, SMEM_BYTES, stream>>>(
            emb, w_lin, (const u16*)nullptr, b_lin, w_att, b_att, w_out, b_out,
            ctx_ids, ctx_len, tgt_ids, tgt_len, tgt_loc, out);
    }
}

// Round 6
// 36.249 us; speedup vs baseline: 5.3502x; 1.5790x over previous
//
#include <hip/hip_runtime.h>

typedef unsigned short u16;
typedef unsigned int   u32;
typedef __fp16 h2t __attribute__((ext_vector_type(2)));

#define D      300
#define L      256
#define LT     8
#define B      256
#define NHOPS  6
#define NCLS   3
#define NT     1024
#define NKP    156          // padded k-pairs (312 k, rows 300..311 zero)

// LDS layout (bytes)
#define OFF_E    0          // u32 [128 lp][300 col] f16x2 pairs  153600
#define OFF_VEC  153600     // f32 [312] (300 + zero pad)          1248
#define OFF_VPK  154848     // u32 [156] vec f16 pairs              624
#define OFF_APK  155472     // u32 [128] alpha f16 pairs            512
#define OFF_S0   155984     // f32 [256]                           1024
#define OFF_CTX  157008     // i32 [256]                           1024
#define SMEM_BYTES 158032

#define DPP_ADD(x, ctrl) \
    x += __int_as_float(__builtin_amdgcn_update_dpp(0, __float_as_int(x), ctrl, 0xf, 0xf, true))

__device__ __forceinline__ float dpp_wave_sum(float x) {
    DPP_ADD(x, 0x111);   // row_shr:1
    DPP_ADD(x, 0x112);   // row_shr:2
    DPP_ADD(x, 0x114);   // row_shr:4
    DPP_ADD(x, 0x118);   // row_shr:8
    DPP_ADD(x, 0x142);   // row_bcast:15
    DPP_ADD(x, 0x143);   // row_bcast:31
    return x;            // lane 63 holds the full 64-lane sum
}
__device__ __forceinline__ float lane63(float x) {
    return __int_as_float(__builtin_amdgcn_readlane(__float_as_int(x), 63));
}
__device__ __forceinline__ u32 pk16(float a, float b) {
    h2t r = __builtin_amdgcn_cvt_pkrtz(a, b);
    return __builtin_bit_cast(u32, r);
}
__device__ __forceinline__ float fdot2(u32 a, u32 b, float c) {
    return __builtin_amdgcn_fdot2(__builtin_bit_cast(h2t, a),
                                  __builtin_bit_cast(h2t, b), c, false);
}

__launch_bounds__(NT, 1)
__global__ void cvt_wpk(const float* __restrict__ w, u32* __restrict__ o) {
    int idx = blockIdx.x * NT + threadIdx.x;
    if (idx < NKP * D) {
        int kp = idx / D, col = idx - kp * D;
        int k0 = 2 * kp;
        float a = (k0     < D) ? w[k0 * D + col]       : 0.f;
        float b = (k0 + 1 < D) ? w[(k0 + 1) * D + col] : 0.f;
        o[idx] = pk16(a, b);
    }
}

template<int WPK>
__launch_bounds__(NT, 1)
__global__ void memnet_main(
    const float* __restrict__ emb,
    const float* __restrict__ w_lin,
    const u32*  __restrict__ wpk,
    const float* __restrict__ b_lin,
    const float* __restrict__ w_att,
    const float* __restrict__ b_att,
    const float* __restrict__ w_out,
    const float* __restrict__ b_out,
    const int* __restrict__ ctx_ids,
    const int* __restrict__ ctx_len,
    const int* __restrict__ tgt_ids,
    const int* __restrict__ tgt_len,
    const int* __restrict__ tgt_loc,
    float* __restrict__ out)
{
    extern __shared__ char sm[];
    float* vec_ = (float*)(sm + OFF_VEC);
    u32*   vpk_ = (u32*)(sm + OFF_VPK);
    u32*   apk_ = (u32*)(sm + OFF_APK);
    float* s0_  = (float*)(sm + OFF_S0);
    int*   ctx_ = (int*)(sm + OFF_CTX);

    const int b = blockIdx.x, t = threadIdx.x;
    const int lane = t & 63, wv = t >> 6;
    const int c  = lane / 5;            // chunk 0..11 (lane<60)
    const int qi = lane - 5 * c;
    const int q  = 5 * wv + qi;         // column quad (heavy)
    const bool heavy = (wv < 15) && (lane < 60);

    const int clen = ctx_len[b], tlen = tgt_len[b], loc = tgt_loc[b];
    const int lps  = (clen + 1) >> 1;   // staged l-pairs

    // ---------------- init ----------------
    if (t < L) { ctx_[t] = ctx_ids[b * L + t]; s0_[t] = 0.f; }
    if (t >= 300 && t < 312) vec_[t] = 0.f;
    if (t < 6) vpk_[150 + t] = 0;
    __syncthreads();

    // ---------------- staging: E pairs (f16x2, vloc-premult) + s0 ----------------
    {
        const float4 z4 = make_float4(0.f, 0.f, 0.f, 0.f);
        float4 wa1 = ((const float4*)w_att)[lane];
        float4 wa2 = z4;
        if (lane < 11) wa2 = ((const float4*)w_att)[64 + lane];
        const float rclen = 1.f / (float)clen;
        for (int lp = wv; lp < lps; lp += 16) {
            const int l0 = 2 * lp, l1 = l0 + 1;
            const float4* e0 = (const float4*)(emb + (long)ctx_[l0] * D);
            const float4* e1 = (const float4*)(emb + (long)ctx_[l1] * D);
            const float4 a0 = e0[lane];
            const float4 a1 = e1[lane];
            float4 b0 = z4, b1 = z4;
            if (lane < 11) { b0 = e0[64 + lane]; b1 = e1[64 + lane]; }
            float d0 = a0.x*wa1.x + a0.y*wa1.y + a0.z*wa1.z + a0.w*wa1.w
                     + b0.x*wa2.x + b0.y*wa2.y + b0.z*wa2.z + b0.w*wa2.w;
            float d1 = a1.x*wa1.x + a1.y*wa1.y + a1.z*wa1.z + a1.w*wa1.w
                     + b1.x*wa2.x + b1.y*wa2.y + b1.z*wa2.z + b1.w*wa2.w;
            d0 = dpp_wave_sum(d0);
            d1 = dpp_wave_sum(d1);
            const float vl0 = 1.f - fabsf((float)(l0 - loc)) * rclen; // l0 < clen
            const float vl1 = (l1 < clen) ? 1.f - fabsf((float)(l1 - loc)) * rclen : 0.f;
            if (lane == 63) { s0_[l0] = vl0 * d0; s0_[l1] = vl1 * d1; }
            uint4 P;
            P.x = pk16(a0.x * vl0, a1.x * vl1);
            P.y = pk16(a0.y * vl0, a1.y * vl1);
            P.z = pk16(a0.z * vl0, a1.z * vl1);
            P.w = pk16(a0.w * vl0, a1.w * vl1);
            *(uint4*)(sm + OFF_E + (lp * 300 + 4 * lane) * 4) = P;
            if (lane < 11) {
                uint4 Q;
                Q.x = pk16(b0.x * vl0, b1.x * vl1);
                Q.y = pk16(b0.y * vl0, b1.y * vl1);
                Q.z = pk16(b0.z * vl0, b1.z * vl1);
                Q.w = pk16(b0.w * vl0, b1.w * vl1);
                *(uint4*)(sm + OFF_E + (lp * 300 + 256 + 4 * lane) * 4) = Q;
            }
        }
    }

    // ---------------- v_aspect -> vec (f32 + f16 pairs) ----------------
    if (t < D) {
        float s = 0.f;
        for (int j = 0; j < tlen; ++j)
            s += emb[(long)tgt_ids[b * LT + j] * D + t];
        const float v = s / (float)tlen;
        vec_[t] = v;
        const float v2 = __shfl_xor(v, 1);
        if ((t & 1) == 0) vpk_[t >> 1] = pk16(v, v2);
    }

    // ---------------- persistent registers ----------------
    uint4 wreg[13];
    if (WPK && heavy) {
        #pragma unroll
        for (int i = 0; i < 13; ++i)
            wreg[i] = *(const uint4*)(wpk + (13 * c + i) * 300 + 4 * q);
    }
    const float4 z4 = make_float4(0.f, 0.f, 0.f, 0.f);
    float4 blin4 = z4;
    if (heavy) blin4 = *(const float4*)(b_lin + 4 * q);
    __syncthreads();   // E, s0, vec, vpk ready

    float4 s0r = z4, wb1 = z4, wb2 = z4;
    float batt = 0.f;
    if (wv == 15) {
        s0r = *(const float4*)(s0_ + 4 * lane);
        wb1 = *(const float4*)(w_att + D + 4 * lane);
        if (lane < 11) wb2 = *(const float4*)(w_att + D + 256 + 4 * lane);
        batt = b_att[0];
    }

    // ---------------- hops ----------------
    for (int hop = 0; hop < NHOPS; ++hop) {
        float4 acc = z4;
        if (heavy) {
            // linear: 13 k-pairs x 4 cols via fdot2
            const u32* vp = vpk_ + 13 * c;
            #pragma unroll
            for (int i = 0; i < 13; ++i) {
                const u32 v2 = vp[i];
                if (WPK) {
                    const uint4 w4 = wreg[i];
                    acc.x = fdot2(v2, w4.x, acc.x);
                    acc.y = fdot2(v2, w4.y, acc.y);
                    acc.z = fdot2(v2, w4.z, acc.z);
                    acc.w = fdot2(v2, w4.w, acc.w);
                } else {
                    const int k0 = 26 * c + 2 * i;
                    const float4 w0 = (k0     < D) ? *(const float4*)(w_lin + (long)k0 * D + 4 * q) : z4;
                    const float4 w1 = (k0 + 1 < D) ? *(const float4*)(w_lin + (long)(k0 + 1) * D + 4 * q) : z4;
                    const float v0 = vec_[k0], v1 = vec_[k0 + 1];
                    acc.x += v0 * w0.x + v1 * w1.x;
                    acc.y += v0 * w0.y + v1 * w1.y;
                    acc.z += v0 * w0.z + v1 * w1.z;
                    acc.w += v0 * w0.w + v1 * w1.w;
                }
            }
        } else if (wv == 15) {
            // tb = vec . w_att[D:] + b_att
            const float4 v1 = *(const float4*)(vec_ + 4 * lane);
            float4 v2 = z4;
            if (lane < 11) v2 = *(const float4*)(vec_ + 256 + 4 * lane);
            float p = v1.x*wb1.x + v1.y*wb1.y + v1.z*wb1.z + v1.w*wb1.w
                    + v2.x*wb2.x + v2.y*wb2.y + v2.z*wb2.z + v2.w*wb2.w;
            p = dpp_wave_sum(p);
            const float tb = lane63(p) + batt;
            // scores: tanh in (-1,1) -> exp safe, no max pass
            const int lb = 4 * lane;
            float e0 = 0.f, e1 = 0.f, e2 = 0.f, e3 = 0.f;
            {
                float x, E2, th;
                x = s0r.x + tb; E2 = __expf(2.f * x);
                th = 1.f - 2.f * __builtin_amdgcn_rcpf(E2 + 1.f);
                if (lb + 0 < clen) e0 = __expf(th);
                x = s0r.y + tb; E2 = __expf(2.f * x);
                th = 1.f - 2.f * __builtin_amdgcn_rcpf(E2 + 1.f);
                if (lb + 1 < clen) e1 = __expf(th);
                x = s0r.z + tb; E2 = __expf(2.f * x);
                th = 1.f - 2.f * __builtin_amdgcn_rcpf(E2 + 1.f);
                if (lb + 2 < clen) e2 = __expf(th);
                x = s0r.w + tb; E2 = __expf(2.f * x);
                th = 1.f - 2.f * __builtin_amdgcn_rcpf(E2 + 1.f);
                if (lb + 3 < clen) e3 = __expf(th);
            }
            float es = dpp_wave_sum(e0 + e1 + e2 + e3);
            const float rinv = __builtin_amdgcn_rcpf(lane63(es));
            *(uint2*)(sm + OFF_APK + 8 * lane) =
                make_uint2(pk16(e0 * rinv, e1 * rinv), pk16(e2 * rinv, e3 * rinv));
        }
        __syncthreads();   // apk ready

        if (heavy) {
            // attention gather: 11 l-pairs x 4 cols from LDS E
            const int lp0 = 11 * c;
            const u32* ap = apk_ + lp0;
            const char* ep = sm + OFF_E + (lp0 * 300 + 4 * q) * 4;
            #pragma unroll
            for (int r = 0; r < 11; ++r) {
                if (lp0 + r < lps) {
                    const u32 av2 = ap[r];
                    const uint4 e4 = *(const uint4*)(ep + r * 1200);
                    acc.x = fdot2(av2, e4.x, acc.x);
                    acc.y = fdot2(av2, e4.y, acc.y);
                    acc.z = fdot2(av2, e4.z, acc.z);
                    acc.w = fdot2(av2, e4.w, acc.w);
                }
            }
            // combine over 12 chunks (lane stride 5): 3-level shfl tree
            float4 s;
            s.x = __shfl(acc.x, lane + 30); s.y = __shfl(acc.y, lane + 30);
            s.z = __shfl(acc.z, lane + 30); s.w = __shfl(acc.w, lane + 30);
            if (c < 6) { acc.x += s.x; acc.y += s.y; acc.z += s.z; acc.w += s.w; }
            s.x = __shfl(acc.x, lane + 15); s.y = __shfl(acc.y, lane + 15);
            s.z = __shfl(acc.z, lane + 15); s.w = __shfl(acc.w, lane + 15);
            if (c < 3) { acc.x += s.x; acc.y += s.y; acc.z += s.z; acc.w += s.w; }
            float4 u1, u2;
            u1.x = __shfl(acc.x, lane + 5);  u1.y = __shfl(acc.y, lane + 5);
            u1.z = __shfl(acc.z, lane + 5);  u1.w = __shfl(acc.w, lane + 5);
            u2.x = __shfl(acc.x, lane + 10); u2.y = __shfl(acc.y, lane + 10);
            u2.z = __shfl(acc.z, lane + 10); u2.w = __shfl(acc.w, lane + 10);
            if (c == 0) {
                float4 nv;
                nv.x = acc.x + u1.x + u2.x + blin4.x;
                nv.y = acc.y + u1.y + u2.y + blin4.y;
                nv.z = acc.z + u1.z + u2.z + blin4.z;
                nv.w = acc.w + u1.w + u2.w + blin4.w;
                *(float4*)(vec_ + 4 * q) = nv;
                *(uint2*)(sm + OFF_VPK + 8 * q) =
                    make_uint2(pk16(nv.x, nv.y), pk16(nv.z, nv.w));
            }
        }
        __syncthreads();   // vec ready
    }

    // ---------------- logits ----------------
    if (wv < NCLS) {
        float p = 0.f;
        for (int i = lane; i < D; i += 64)
            p += vec_[i] * w_out[i * NCLS + wv];
        p = dpp_wave_sum(p);
        if (lane == 63) out[b * NCLS + wv] = p + b_out[wv];
    }
}

extern "C" void kernel_launch(void* const* d_in, const int* in_sizes, int n_in,
                              void* d_out, int out_size, void* d_ws, size_t ws_size,
                              hipStream_t stream) {
    const float* emb     = (const float*)d_in[0];
    const float* w_lin   = (const float*)d_in[1];
    const float* b_lin   = (const float*)d_in[2];
    const float* w_att   = (const float*)d_in[3];
    const float* b_att   = (const float*)d_in[4];
    const float* w_out   = (const float*)d_in[5];
    const float* b_out   = (const float*)d_in[6];
    const int*   ctx_ids = (const int*)d_in[7];
    const int*   ctx_len = (const int*)d_in[8];
    const int*   tgt_ids = (const int*)d_in[9];
    const int*   tgt_len = (const int*)d_in[10];
    const int*   tgt_loc = (const int*)d_in[11];
    float* out = (float*)d_out;

    const size_t WBYTES = (size_t)NKP * D * sizeof(u32);   // 187200
    if (ws_size >= WBYTES) {
        u32* wpk = (u32*)d_ws;
        cvt_wpk<<<(NKP * D + NT - 1) / NT, NT, 0, stream>>>(w_lin, wpk);
        (void)hipFuncSetAttribute((const void*)memnet_main<1>,
                                  hipFuncAttributeMaxDynamicSharedMemorySize,
                                  SMEM_BYTES);
        memnet_main<1><<<B, NT, SMEM_BYTES, stream>>>(
            emb, w_lin, wpk, b_lin, w_att, b_att, w_out, b_out,
            ctx_ids, ctx_len, tgt_ids, tgt_len, tgt_loc, out);
    } else {
        (void)hipFuncSetAttribute((const void*)memnet_main<0>,
                                  hipFuncAttributeMaxDynamicSharedMemorySize,
                                  SMEM_BYTES);
        memnet_main<0><<<B, NT, SMEM_BYTES, stream>>>(
            emb, w_lin, (const u32*)nullptr, b_lin, w_att, b_att, w_out, b_out,
            ctx_ids, ctx_len, tgt_ids, tgt_len, tgt_loc, out);
    }
}

// Round 7
// 34.046 us; speedup vs baseline: 5.6963x; 1.0647x over previous
//
#include <hip/hip_runtime.h>

typedef unsigned short u16;
typedef unsigned int   u32;
typedef __fp16 h2t __attribute__((ext_vector_type(2)));

#define D      300
#define L      256
#define LT     8
#define B      256
#define NHOPS  6
#define NCLS   3
#define NT     1024

// LDS layout (bytes)
#define OFF_E    0          // u32 [128 lp][300 col] f16x2 pairs  153600
#define OFF_VEC  153600     // f32 [312] (300 + zero pad)          1248
#define OFF_VPK  154848     // u32 [12 chunks][20] vec f16 pairs    960
#define OFF_APK  155808     // u32 [12 chunks][12] alpha f16 pairs  576
#define OFF_S0   156384     // f32 [256]                           1024
#define OFF_CTX  157408     // i32 [256]                           1024
#define SMEM_BYTES 158432

#define DPP_ADD(x, ctrl) \
    x += __int_as_float(__builtin_amdgcn_update_dpp(0, __float_as_int(x), ctrl, 0xf, 0xf, true))

__device__ __forceinline__ float dpp_wave_sum(float x) {
    DPP_ADD(x, 0x111);   // row_shr:1
    DPP_ADD(x, 0x112);   // row_shr:2
    DPP_ADD(x, 0x114);   // row_shr:4
    DPP_ADD(x, 0x118);   // row_shr:8
    DPP_ADD(x, 0x142);   // row_bcast:15
    DPP_ADD(x, 0x143);   // row_bcast:31
    return x;            // lane 63 holds the full 64-lane sum
}
__device__ __forceinline__ float lane63(float x) {
    return __int_as_float(__builtin_amdgcn_readlane(__float_as_int(x), 63));
}
__device__ __forceinline__ u32 pk16(float a, float b) {
    h2t r = __builtin_amdgcn_cvt_pkrtz(a, b);
    return __builtin_bit_cast(u32, r);
}
__device__ __forceinline__ float fdot2(u32 a, u32 b, float c) {
    return __builtin_amdgcn_fdot2(__builtin_bit_cast(h2t, a),
                                  __builtin_bit_cast(h2t, b), c, false);
}

__launch_bounds__(NT, 1)
__global__ void memnet_main(
    const float* __restrict__ emb,
    const float* __restrict__ w_lin,
    const float* __restrict__ b_lin,
    const float* __restrict__ w_att,
    const float* __restrict__ b_att,
    const float* __restrict__ w_out,
    const float* __restrict__ b_out,
    const int* __restrict__ ctx_ids,
    const int* __restrict__ ctx_len,
    const int* __restrict__ tgt_ids,
    const int* __restrict__ tgt_len,
    const int* __restrict__ tgt_loc,
    float* __restrict__ out)
{
    extern __shared__ char sm[];
    float* vec_ = (float*)(sm + OFF_VEC);
    u32*   vpk_ = (u32*)(sm + OFF_VPK);
    u32*   apk_ = (u32*)(sm + OFF_APK);
    float* s0_  = (float*)(sm + OFF_S0);
    int*   ctx_ = (int*)(sm + OFF_CTX);

    const int b = blockIdx.x, t = threadIdx.x;
    const int lane = t & 63, wv = t >> 6;
    const int c  = lane / 5;            // chunk 0..11 (lane<60)
    const int qi = lane - 5 * c;
    const int q  = 5 * wv + qi;         // column quad (heavy)
    const bool heavy = (wv < 15) && (lane < 60);

    const int clen = ctx_len[b], tlen = tgt_len[b], loc = tgt_loc[b];
    const int lps  = (clen + 1) >> 1;   // staged l-pairs

    const float4 z4 = make_float4(0.f, 0.f, 0.f, 0.f);

    // ---------------- init ----------------
    if (t < L) { ctx_[t] = ctx_ids[b * L + t]; s0_[t] = 0.f; }
    if (t >= 300 && t < 312) vec_[t] = 0.f;
    if (t >= 768 && t < 1008) vpk_[t - 768] = 0;   // zero all 240 slots
    __syncthreads();

    // ---------------- W pack into registers (f16 pairs, reused 6 hops) ----
    // wreg[i] covers k-pair (26c+2i, 26c+2i+1), cols 4q..4q+3
    uint4 wreg[13];
    if (heavy) {
        #pragma unroll
        for (int i = 0; i < 13; ++i) {
            const int k0 = 26 * c + 2 * i;
            float4 w0 = z4, w1 = z4;
            if (k0 < D)     w0 = *(const float4*)(w_lin + (long)k0 * D + 4 * q);
            if (k0 + 1 < D) w1 = *(const float4*)(w_lin + (long)(k0 + 1) * D + 4 * q);
            wreg[i].x = pk16(w0.x, w1.x);
            wreg[i].y = pk16(w0.y, w1.y);
            wreg[i].z = pk16(w0.z, w1.z);
            wreg[i].w = pk16(w0.w, w1.w);
        }
    }

    // ---------------- staging: E pairs (f16x2, vloc-premult) + s0 ----------------
    {
        float4 wa1 = ((const float4*)w_att)[lane];
        float4 wa2 = z4;
        if (lane < 11) wa2 = ((const float4*)w_att)[64 + lane];
        const float rclen = 1.f / (float)clen;
        for (int lp = wv; lp < lps; lp += 16) {
            const int l0 = 2 * lp, l1 = l0 + 1;
            const float4* e0 = (const float4*)(emb + (long)ctx_[l0] * D);
            const float4* e1 = (const float4*)(emb + (long)ctx_[l1] * D);
            const float4 a0 = e0[lane];
            const float4 a1 = e1[lane];
            float4 b0 = z4, b1 = z4;
            if (lane < 11) { b0 = e0[64 + lane]; b1 = e1[64 + lane]; }
            float d0 = a0.x*wa1.x + a0.y*wa1.y + a0.z*wa1.z + a0.w*wa1.w
                     + b0.x*wa2.x + b0.y*wa2.y + b0.z*wa2.z + b0.w*wa2.w;
            float d1 = a1.x*wa1.x + a1.y*wa1.y + a1.z*wa1.z + a1.w*wa1.w
                     + b1.x*wa2.x + b1.y*wa2.y + b1.z*wa2.z + b1.w*wa2.w;
            d0 = dpp_wave_sum(d0);
            d1 = dpp_wave_sum(d1);
            const float vl0 = 1.f - fabsf((float)(l0 - loc)) * rclen; // l0 < clen
            const float vl1 = (l1 < clen) ? 1.f - fabsf((float)(l1 - loc)) * rclen : 0.f;
            if (lane == 63) { s0_[l0] = vl0 * d0; s0_[l1] = vl1 * d1; }
            uint4 P;
            P.x = pk16(a0.x * vl0, a1.x * vl1);
            P.y = pk16(a0.y * vl0, a1.y * vl1);
            P.z = pk16(a0.z * vl0, a1.z * vl1);
            P.w = pk16(a0.w * vl0, a1.w * vl1);
            *(uint4*)(sm + OFF_E + (lp * 300 + 4 * lane) * 4) = P;
            if (lane < 11) {
                uint4 Q;
                Q.x = pk16(b0.x * vl0, b1.x * vl1);
                Q.y = pk16(b0.y * vl0, b1.y * vl1);
                Q.z = pk16(b0.z * vl0, b1.z * vl1);
                Q.w = pk16(b0.w * vl0, b1.w * vl1);
                *(uint4*)(sm + OFF_E + (lp * 300 + 256 + 4 * lane) * 4) = Q;
            }
        }
    }

    // ---------------- v_aspect -> vec (f32 + padded f16 pairs) ----------------
    if (t < D) {
        int ids[LT];
        #pragma unroll
        for (int j = 0; j < LT; ++j) ids[j] = tgt_ids[b * LT + j];  // uniform -> s_load
        float s = 0.f;
        #pragma unroll
        for (int j = 0; j < LT; ++j) {
            const int  safe = (j < tlen) ? ids[j] : ids[0];
            const float msk = (j < tlen) ? 1.f : 0.f;
            s += msk * emb[(long)safe * D + t];
        }
        const float v = s / (float)tlen;
        vec_[t] = v;
        const float v2 = __shfl_xor(v, 1);
        if ((t & 1) == 0) {
            const int kp = t >> 1;
            const int cp = kp / 13, sl = kp - 13 * cp;
            vpk_[20 * cp + sl] = pk16(v, v2);
        }
    }

    float4 blin4 = z4;
    if (heavy) blin4 = *(const float4*)(b_lin + 4 * q);
    __syncthreads();   // E, s0, vec, vpk ready

    float4 s0r = z4, wb1 = z4, wb2 = z4;
    float batt = 0.f;
    if (wv == 15) {
        s0r = *(const float4*)(s0_ + 4 * lane);
        wb1 = *(const float4*)(w_att + D + 4 * lane);
        if (lane < 11) wb2 = *(const float4*)(w_att + D + 256 + 4 * lane);
        batt = b_att[0];
    }

    // ---------------- hops ----------------
    for (int hop = 0; hop < NHOPS; ++hop) {
        float4 acc = z4;
        if (heavy) {
            // linear: 13 k-pairs x 4 cols via fdot2 (vec pairs: 4 b128 reads)
            const uint4* vp4 = (const uint4*)(vpk_ + 20 * c);
            const uint4 V0 = vp4[0], V1 = vp4[1], V2 = vp4[2], V3 = vp4[3];
            const u32 vs[13] = {V0.x, V0.y, V0.z, V0.w,
                                V1.x, V1.y, V1.z, V1.w,
                                V2.x, V2.y, V2.z, V2.w, V3.x};
            #pragma unroll
            for (int i = 0; i < 13; ++i) {
                acc.x = fdot2(vs[i], wreg[i].x, acc.x);
                acc.y = fdot2(vs[i], wreg[i].y, acc.y);
                acc.z = fdot2(vs[i], wreg[i].z, acc.z);
                acc.w = fdot2(vs[i], wreg[i].w, acc.w);
            }
        } else if (wv == 15) {
            __builtin_amdgcn_s_setprio(1);
            // tb = vec . w_att[D:] + b_att
            const float4 v1 = *(const float4*)(vec_ + 4 * lane);
            float4 v2 = z4;
            if (lane < 11) v2 = *(const float4*)(vec_ + 256 + 4 * lane);
            float p = v1.x*wb1.x + v1.y*wb1.y + v1.z*wb1.z + v1.w*wb1.w
                    + v2.x*wb2.x + v2.y*wb2.y + v2.z*wb2.z + v2.w*wb2.w;
            p = dpp_wave_sum(p);
            const float tb = lane63(p) + batt;
            // scores: tanh in (-1,1) -> exp safe, no max pass
            const int lb = 4 * lane;
            float e0 = 0.f, e1 = 0.f, e2 = 0.f, e3 = 0.f;
            {
                float x, E2, th;
                x = s0r.x + tb; E2 = __expf(2.f * x);
                th = 1.f - 2.f * __builtin_amdgcn_rcpf(E2 + 1.f);
                if (lb + 0 < clen) e0 = __expf(th);
                x = s0r.y + tb; E2 = __expf(2.f * x);
                th = 1.f - 2.f * __builtin_amdgcn_rcpf(E2 + 1.f);
                if (lb + 1 < clen) e1 = __expf(th);
                x = s0r.z + tb; E2 = __expf(2.f * x);
                th = 1.f - 2.f * __builtin_amdgcn_rcpf(E2 + 1.f);
                if (lb + 2 < clen) e2 = __expf(th);
                x = s0r.w + tb; E2 = __expf(2.f * x);
                th = 1.f - 2.f * __builtin_amdgcn_rcpf(E2 + 1.f);
                if (lb + 3 < clen) e3 = __expf(th);
            }
            float es = dpp_wave_sum(e0 + e1 + e2 + e3);
            const float rinv = __builtin_amdgcn_rcpf(lane63(es));
            // alpha pairs -> chunk-padded layout [cp][12]
            const int p0 = 2 * lane, p1 = p0 + 1;
            const int c0 = p0 / 11, sl0 = p0 - 11 * c0;
            const int c1 = p1 / 11, sl1 = p1 - 11 * c1;
            apk_[12 * c0 + sl0] = pk16(e0 * rinv, e1 * rinv);
            apk_[12 * c1 + sl1] = pk16(e2 * rinv, e3 * rinv);
            __builtin_amdgcn_s_setprio(0);
        }
        __syncthreads();   // apk ready

        if (heavy) {
            // attention gather: 11 l-pairs x 4 cols from LDS E (alphas: 3 b128)
            const uint4* ap4 = (const uint4*)(apk_ + 12 * c);
            const uint4 A0 = ap4[0], A1 = ap4[1], A2 = ap4[2];
            const u32 as[12] = {A0.x, A0.y, A0.z, A0.w,
                                A1.x, A1.y, A1.z, A1.w,
                                A2.x, A2.y, A2.z, A2.w};
            const int lp0 = 11 * c;
            const char* ep = sm + OFF_E + (lp0 * 300 + 4 * q) * 4;
            #pragma unroll
            for (int r = 0; r < 11; ++r) {
                if (lp0 + r < lps) {
                    const uint4 e4 = *(const uint4*)(ep + r * 1200);
                    acc.x = fdot2(as[r], e4.x, acc.x);
                    acc.y = fdot2(as[r], e4.y, acc.y);
                    acc.z = fdot2(as[r], e4.z, acc.z);
                    acc.w = fdot2(as[r], e4.w, acc.w);
                }
            }
            // combine over 12 chunks (lane stride 5): 3-level shfl tree
            float4 s;
            s.x = __shfl(acc.x, lane + 30); s.y = __shfl(acc.y, lane + 30);
            s.z = __shfl(acc.z, lane + 30); s.w = __shfl(acc.w, lane + 30);
            if (c < 6) { acc.x += s.x; acc.y += s.y; acc.z += s.z; acc.w += s.w; }
            s.x = __shfl(acc.x, lane + 15); s.y = __shfl(acc.y, lane + 15);
            s.z = __shfl(acc.z, lane + 15); s.w = __shfl(acc.w, lane + 15);
            if (c < 3) { acc.x += s.x; acc.y += s.y; acc.z += s.z; acc.w += s.w; }
            float4 u1, u2;
            u1.x = __shfl(acc.x, lane + 5);  u1.y = __shfl(acc.y, lane + 5);
            u1.z = __shfl(acc.z, lane + 5);  u1.w = __shfl(acc.w, lane + 5);
            u2.x = __shfl(acc.x, lane + 10); u2.y = __shfl(acc.y, lane + 10);
            u2.z = __shfl(acc.z, lane + 10); u2.w = __shfl(acc.w, lane + 10);
            if (c == 0) {
                float4 nv;
                nv.x = acc.x + u1.x + u2.x + blin4.x;
                nv.y = acc.y + u1.y + u2.y + blin4.y;
                nv.z = acc.z + u1.z + u2.z + blin4.z;
                nv.w = acc.w + u1.w + u2.w + blin4.w;
                *(float4*)(vec_ + 4 * q) = nv;
                const int p0 = 2 * q, p1 = p0 + 1;
                const int ca = p0 / 13, sa = p0 - 13 * ca;
                const int cb = p1 / 13, sb = p1 - 13 * cb;
                vpk_[20 * ca + sa] = pk16(nv.x, nv.y);
                vpk_[20 * cb + sb] = pk16(nv.z, nv.w);
            }
        }
        __syncthreads();   // vec + vpk ready
    }

    // ---------------- logits ----------------
    if (wv < NCLS) {
        float p = 0.f;
        for (int i = lane; i < D; i += 64)
            p += vec_[i] * w_out[i * NCLS + wv];
        p = dpp_wave_sum(p);
        if (lane == 63) out[b * NCLS + wv] = p + b_out[wv];
    }
}

extern "C" void kernel_launch(void* const* d_in, const int* in_sizes, int n_in,
                              void* d_out, int out_size, void* d_ws, size_t ws_size,
                              hipStream_t stream) {
    const float* emb     = (const float*)d_in[0];
    const float* w_lin   = (const float*)d_in[1];
    const float* b_lin   = (const float*)d_in[2];
    const float* w_att   = (const float*)d_in[3];
    const float* b_att   = (const float*)d_in[4];
    const float* w_out   = (const float*)d_in[5];
    const float* b_out   = (const float*)d_in[6];
    const int*   ctx_ids = (const int*)d_in[7];
    const int*   ctx_len = (const int*)d_in[8];
    const int*   tgt_ids = (const int*)d_in[9];
    const int*   tgt_len = (const int*)d_in[10];
    const int*   tgt_loc = (const int*)d_in[11];
    float* out = (float*)d_out;

    (void)hipFuncSetAttribute((const void*)memnet_main,
                              hipFuncAttributeMaxDynamicSharedMemorySize,
                              SMEM_BYTES);
    memnet_main<<<B, NT, SMEM_BYTES, stream>>>(
        emb, w_lin, b_lin, w_att, b_att, w_out, b_out,
        ctx_ids, ctx_len, tgt_ids, tgt_len, tgt_loc, out);
}